// Round 1
// baseline (1388.179 us; speedup 1.0000x reference)
//
#include <hip/hip_runtime.h>
#include <hip/hip_bf16.h>
#include <math.h>

// Unicycle rollout: out[0] = x0, out[t+1] = x0 + sum_{k<=t} 0.1*[cos(a_k), sin(a_k)],
// a_k = tanh(u[k]) * pi/6.  One thread per column b; sequential scan over T.
// All loads/stores coalesced (lane i -> column base+i).

__global__ __launch_bounds__(256) void rollout_kernel(
    const float* __restrict__ x0,   // [2, B]
    const float* __restrict__ u,    // [T, B]
    float* __restrict__ out,        // [T+1, 2, B]
    int B, int T)
{
    const int b = blockIdx.x * blockDim.x + threadIdx.x;
    if (b >= B) return;

    const float C_ANG = 0.52359877559829887f;  // pi/6
    const float DT    = 0.1f;

    float x = x0[b];
    float y = x0[B + b];

    // row 0 = x0
    out[b]     = x;
    out[B + b] = y;

    const float* up = u + b;
    float*       op = out + (size_t)2 * B + b;   // row t+1 starts here
    const size_t ostride = (size_t)2 * B;

    #pragma unroll 4
    for (int t = 0; t < T; ++t) {
        float ut = up[(size_t)t * B];

        // tanh(ut) = 1 - 2/(exp(2*ut)+1)   (stable for large |ut|)
        float e  = __expf(2.0f * ut);
        float th = 1.0f - 2.0f * __builtin_amdgcn_rcpf(e + 1.0f);
        float ang = th * C_ANG;

        // |ang| <= pi/6 -> hardware sin/cos, no range reduction worries
        float s = __sinf(ang);
        float c = __cosf(ang);

        x += DT * c;
        y += DT * s;

        op[0] = x;
        op[B] = y;
        op += ostride;
    }
}

extern "C" void kernel_launch(void* const* d_in, const int* in_sizes, int n_in,
                              void* d_out, int out_size, void* d_ws, size_t ws_size,
                              hipStream_t stream) {
    const float* x0 = (const float*)d_in[0];   // [2, B]
    const float* u  = (const float*)d_in[1];   // [T, B]
    float* out = (float*)d_out;                // [T+1, 2, B]

    const int B = in_sizes[0] / 2;
    const int T = in_sizes[1] / B;

    const int block = 256;
    const int grid  = (B + block - 1) / block;
    rollout_kernel<<<grid, block, 0, stream>>>(x0, u, out, B, T);
}